// Round 8
// baseline (1252.641 us; speedup 1.0000x reference)
//
#include <hip/hip_runtime.h>
#include <cstdint>
#include <cstddef>

#define BB 16
#define NN 4096
#define SS 1024
#define KK 32
#define MROWS (BB*SS*KK)   // 524288 rows, one per (b,s,k)
#define EPSV 1e-5f
#define OUT_OFF1 (BB*3*SS) // 49152 floats: new_xyz chunk size

// ---------------- workspace layout (bytes) ----------------
static constexpr size_t OFF_XYZT   = 0;                                    // float4[B*N]
static constexpr size_t OFF_NEWXYZ = OFF_XYZT   + (size_t)BB*NN*16;        // float4[B*S]
static constexpr size_t OFF_BALL   = OFF_NEWXYZ + (size_t)BB*SS*16;        // int[M] (unused now)
static constexpr size_t OFF_STATS  = OFF_BALL   + (size_t)MROWS*4;         // float[512]
static constexpr size_t OFF_PROG   = OFF_STATS  + 2048;                    // int[64]: [0..15] FPS progress
static constexpr size_t OFF_PT     = OFF_PROG   + 256;                     // float[B*N*64]
static constexpr size_t OFF_Y      = OFF_PT     + (size_t)BB*NN*64*4;      // float[M*64] 134MB
static constexpr size_t OFF_YMAX   = OFF_Y      + (size_t)MROWS*64*4;      // float[B*S*128]
static constexpr size_t OFF_YMIN   = OFF_YMAX   + (size_t)BB*SS*128*4;     // float[B*S*128]

// Non-contractible fp32 ops: numpy computes mul+add (never FMA). hipcc ignores
// `#pragma clang fp contract(off)` for device code (proven rounds 1-8) — the
// _rn intrinsics are the only reliable way to match np's discrete decisions.
__device__ __forceinline__ float sq3(float x, float y, float z) {
  return __fadd_rn(__fadd_rn(__fmul_rn(x,x), __fmul_rn(y,y)), __fmul_rn(z,z));
}

// u64 max with a DPP-shifted partner (r1-proven): VALU-latency lane exchange.
// row_shr:1/2/4/8 + row_bcast15 + row_bcast31; full-wave max lands in lane 63.
template<int CTRL>
__device__ __forceinline__ unsigned long long dpp_max_u64(unsigned long long k) {
  int lo = (int)(unsigned)k;
  int hi = (int)(unsigned)(k >> 32);
  unsigned olo = (unsigned)__builtin_amdgcn_update_dpp(0, lo, CTRL, 0xf, 0xf, true);
  unsigned ohi = (unsigned)__builtin_amdgcn_update_dpp(0, hi, CTRL, 0xf, 0xf, true);
  unsigned long long o = ((unsigned long long)ohi << 32) | (unsigned long long)olo;
  return o > k ? o : k;
}

// ---------------- standalone transpose prologue ----------------
__global__ __launch_bounds__(256) void trans_kernel(const float* __restrict__ xyz,
                                                    const float* __restrict__ pts,
                                                    float4* __restrict__ xyzt,
                                                    float* __restrict__ pt) {
  __shared__ float tl[64*65];
  int t = threadIdx.x;
  int k = blockIdx.x;                 // 1024 blocks: b = k>>6, n0 = (k&63)*64
  int b = k >> 6, n0 = (k & 63) * 64;
  int ln = t & 63, hi = t >> 6;
#pragma unroll
  for (int i = 0; i < 16; ++i) {
    int c = 4*i + hi;
    tl[c*65 + ln] = pts[((size_t)b*64 + c)*NN + n0 + ln];
  }
  if (t < 64) {
    int n = n0 + t;
    const float* xb = xyz + (size_t)b*3*NN;
    xyzt[(size_t)b*NN + n] = make_float4(xb[n], xb[NN+n], xb[2*NN+n], 0.f);
  }
  __syncthreads();
#pragma unroll
  for (int i = 0; i < 16; ++i) {
    int nn = hi + 4*i;
    pt[((size_t)b*NN + n0 + nn)*64 + ln] = tl[ln*65 + nn];
  }
}

// ---------------- mega kernel (r3-exact FPS; 4 failed FPS theories reverted) ----
// blocks 0-15    : FPS (round-10 u64 form + r1 store-batching, barrier reduce)
// blocks 16-4111 : fused ball query + conv0 tile (128 rows each), dependency
//                  prog[b] only (r0/r1-proven safe class).
// LDS union: FPS 65600 B, fused 52736 B -> 65600 B static, 2 blocks/CU.
__global__ __launch_bounds__(256) void fps_ball_conv0(const float* __restrict__ xyz,
                                                      const float4* __restrict__ xyzt,
                                                      const float* __restrict__ pt,
                                                      float4* __restrict__ newxyz,
                                                      int* __restrict__ prog,
                                                      float* __restrict__ out,
                                                      const float* __restrict__ W0,
                                                      const float* __restrict__ bias0,
                                                      float* __restrict__ y,
                                                      float* __restrict__ stats0) {
  __shared__ __align__(16) char smem[65600];
  int t = threadIdx.x;

  if (blockIdx.x >= 16) {
    // ---------------- fused ball query + conv0 (one 128-row tile) ----------------
    float4* Ws4  = (float4*)smem;                 // [0, 17408)   68x64 weights
    float*  Ws   = (float*)Ws4;
    float4* Xs4  = (float4*)(smem + 17408);       // [17408, 52224) 128x68 tile
    int*    bidx = (int*)(smem + 52224);          // [52224, 52736) ball indices
    int lane = t & 63, wv = t >> 6;
    int base = (blockIdx.x - 16)*4;               // 4 consecutive bs
    int bs = base + wv;
    int b = bs >> 10;

    // W0 preload overlaps the wait (no dependency). Column order matches the
    // proven MODE0 layout: [points64, xyz3, zero-pad].
    for (int idx = t; idx < 68*64; idx += 256) {
      int cc = idx >> 6, o = idx & 63;
      float v = 0.f;
      if (cc < 67) v = W0[o*67 + (cc < 64 ? cc+3 : cc-64)];
      Ws[(cc << 6) + o] = v;
    }

    // Single poller (r1 poll-storm fix), FPS progress only.
    int need = (base & (SS-1)) + 4;
    if (t == 0) {
      while (__hip_atomic_load(&prog[b], __ATOMIC_ACQUIRE, __HIP_MEMORY_SCOPE_AGENT) < need)
        __builtin_amdgcn_s_sleep(64);
    }
    __syncthreads();

    // ---- ball query (verified ballot form), indices to LDS ----
    const float* xb = xyz + (size_t)b*3*NN;
    float4 c = newxyz[bs];
    float sumS = sq3(c.x, c.y, c.z);
    int count = 0;
    for (int ch = 0; ch < NN/64; ++ch) {
      int n = ch*64 + lane;
      float nx = xb[n], ny = xb[NN+n], nz = xb[2*NN+n];
      float sumN = sq3(nx, ny, nz);
      float dt   = __fadd_rn(__fadd_rn(__fmul_rn(c.x,nx), __fmul_rn(c.y,ny)), __fmul_rn(c.z,nz));
      float sqr  = __fsub_rn(__fadd_rn(sumS, sumN), __fmul_rn(2.0f, dt));
      bool isin = !(sqr > 0.04f);
      unsigned long long mask = __ballot(isin);
      int pos = count + (int)__popcll(mask & ((1ull << lane) - 1ull));
      if (isin && pos < KK) bidx[(wv << 5) + pos] = n;
      count += (int)__popcll(mask);
      if (count >= KK) break;
    }
    if (count < KK && lane >= count && lane < KK) bidx[(wv << 5) + lane] = NN-1;
    __syncthreads();

    // ---- gather (MODE0 form, ball index from LDS) ----
    {
      int rr = t >> 1, p = t & 1;
      int n = bidx[rr];
      const float4* src = (const float4*)(pt + ((size_t)(b*NN + n))*64) + 8*p;
#pragma unroll
      for (int jj = 0; jj < 8; ++jj) Xs4[rr*17 + 8*p + jj] = src[jj];
      if (p == 0) {
        float4 pz = xyzt[b*NN + n];
        float4 q  = newxyz[base + (rr >> 5)];
        float* X = (float*)Xs4;
        X[rr*68 + 64] = pz.x - q.x;
        X[rr*68 + 65] = pz.y - q.y;
        X[rr*68 + 66] = pz.z - q.z;
        X[rr*68 + 67] = 0.f;
      }
    }
    __syncthreads();

    // ---- conv0 GEMM (exact MODE0 inner loop, CO=64, CR=68) ----
    int tc = t & 15, trs = (t >> 4) & 3;
    float accS[4], accQ[4];
#pragma unroll
    for (int j = 0; j < 4; ++j) { accS[j] = 0.f; accQ[j] = 0.f; }

    float acc[8][4];
#pragma unroll
    for (int i = 0; i < 8; ++i)
#pragma unroll
      for (int j = 0; j < 4; ++j) acc[i][j] = bias0[tc*4 + j];

    for (int c4 = 0; c4 < 17; ++c4) {
      float4 a[8];
#pragma unroll
      for (int i = 0; i < 8; ++i) a[i] = Xs4[(32*wv + trs + 4*i)*17 + c4];
      float4 w[4];
#pragma unroll
      for (int cc = 0; cc < 4; ++cc) w[cc] = Ws4[(4*c4 + cc)*16 + tc];
#pragma unroll
      for (int cc = 0; cc < 4; ++cc) {
#pragma unroll
        for (int i = 0; i < 8; ++i) {
          float av = (cc==0) ? a[i].x : (cc==1) ? a[i].y : (cc==2) ? a[i].z : a[i].w;
          acc[i][0] = fmaf(av, w[cc].x, acc[i][0]);
          acc[i][1] = fmaf(av, w[cc].y, acc[i][1]);
          acc[i][2] = fmaf(av, w[cc].z, acc[i][2]);
          acc[i][3] = fmaf(av, w[cc].w, acc[i][3]);
        }
      }
    }

#pragma unroll
    for (int i = 0; i < 8; ++i) {
      size_t rw = (size_t)base*32 + 32*wv + trs + 4*i;
      ((float4*)(y + rw*64))[tc] = make_float4(acc[i][0], acc[i][1], acc[i][2], acc[i][3]);
    }
#pragma unroll
    for (int i = 0; i < 8; ++i)
#pragma unroll
      for (int j = 0; j < 4; ++j) {
        float v = acc[i][j];
        accS[j] += v;
        accQ[j] = fmaf(v, v, accQ[j]);
      }

    __syncthreads();
    float* scratch = (float*)Xs4;
    if (t < 128) scratch[t] = 0.f;
    __syncthreads();
#pragma unroll
    for (int j = 0; j < 4; ++j) {
      atomicAdd(&scratch[tc*4 + j], accS[j]);
      atomicAdd(&scratch[64 + tc*4 + j], accQ[j]);
    }
    __syncthreads();
    if (t < 128) atomicAdd(&stats0[t], scratch[t]);
    return;
  }

  // ---------------- FPS (round-10 u64 form + r1 store-batch, float4 LDS) ----------------
  float4* sxyz = (float4*)smem;                                   // [0, 65536)
  unsigned long long (*red)[4] = (unsigned long long (*)[4])(smem + 65536);
  int b = blockIdx.x;
  int lane = t & 63, wv = t >> 6;
  const float* xb = xyz + (size_t)b*3*NN;
  float px[16], py[16], pz[16], dd[16];
#pragma unroll
  for (int j = 0; j < 16; ++j) {
    int n = t + 256*j;
    px[j] = xb[n]; py[j] = xb[NN+n]; pz[j] = xb[2*NN+n];
    sxyz[n] = make_float4(px[j], py[j], pz[j], 0.f);
    dd[j] = 1e10f;
  }
  int f = 0;
  float mcx = 0.f, mcy = 0.f, mcz = 0.f;   // captured centroid (wave-0 lanes 0-31)
  __syncthreads();
  for (int i = 0; i < SS; ++i) {
    float4 cc4 = sxyz[f];                  // one ds_read_b128 (uniform broadcast)
    float cx = cc4.x, cy = cc4.y, cz = cc4.z;
    if (t == (i & 31)) { mcx = cx; mcy = cy; mcz = cz; }
    if ((i & 31) == 31) {
      if (t < 32) {
        int ci = i - 31 + t;
        newxyz[b*SS + ci] = make_float4(mcx, mcy, mcz, 0.f);
        out[(size_t)b*3*SS + ci]        = mcx;
        out[(size_t)b*3*SS + SS + ci]   = mcy;
        out[(size_t)b*3*SS + 2*SS + ci] = mcz;
      }
      // release by lane 0: wave-wide vmcnt(0) before the release store covers
      // lanes 1-31's flush stores above.
      if (t == 0)
        __hip_atomic_store(&prog[b], i+1, __ATOMIC_RELEASE, __HIP_MEMORY_SCOPE_AGENT);
    }
    if (i == SS-1) break;
    unsigned long long key[16];
#pragma unroll
    for (int j = 0; j < 16; ++j) {
      float dx = __fsub_rn(px[j], cx);
      float dy = __fsub_rn(py[j], cy);
      float dz = __fsub_rn(pz[j], cz);
      float d  = sq3(dx, dy, dz);                // ((dx^2+dy^2)+dz^2), no FMA
      float nd = dd[j] < d ? dd[j] : d;
      dd[j] = nd;
      key[j] = (((unsigned long long)__float_as_uint(nd)) << 32)
             | (unsigned)(NN-1 - (t + 256*j));
    }
#pragma unroll
    for (int w = 8; w >= 1; w >>= 1)
#pragma unroll
      for (int q = 0; q < w; ++q)
        key[q] = key[q] > key[q+w] ? key[q] : key[q+w];
    unsigned long long bk = key[0];
    bk = dpp_max_u64<0x111>(bk);   // row_shr:1
    bk = dpp_max_u64<0x112>(bk);   // row_shr:2
    bk = dpp_max_u64<0x114>(bk);   // row_shr:4
    bk = dpp_max_u64<0x118>(bk);   // row_shr:8  -> lane 15 of each row16 has row max
    bk = dpp_max_u64<0x142>(bk);   // row_bcast15
    bk = dpp_max_u64<0x143>(bk);   // row_bcast31 -> lane 63 has full-wave max
    if (lane == 63) red[i&1][wv] = bk;
    __syncthreads();
    unsigned long long best = red[i&1][0];
#pragma unroll
    for (int w = 1; w < 4; ++w) { unsigned long long v = red[i&1][w]; if (v > best) best = v; }
    f = (NN-1) - (int)(best & 0xffffffffull);
  }
}

// ---------------- conv passes, X from GLOBAL (r7 post-mortem) ----------------
// Each X element is read by exactly ONE wave (16-lane broadcast over tc), so
// LDS staging bought zero reuse and made the GEMM LDS-pipe-bound (12 ds_read
// per c4 vs ~384cy VALU, shared pipe). Now: a[i] straight from global, BN+relu
// in registers (same values, same FMA order -> bit-identical), W stays in LDS
// (real reuse: read 128x/block). No Xs4, no per-tile barriers.
// In-place safety (MODE1, xin==yout): rows are partitioned per-wave (32wv+trs
// +4i); a wave issues all its reads (c4 loop) before any store (lockstep),
// and blocks own disjoint tiles.
// MODE 1: read y, BN0+relu, conv 64->64, write y in-place, stats1
// MODE 2: read y, BN1+relu, conv 64->128, stats2, per-(b,s) max&min over k
template<int MODE, int CO>
__global__ __launch_bounds__(256) void conv_kernel(
    const float* xin, const float* __restrict__ W, const float* __restrict__ bias,
    const float* __restrict__ statsPrev, const float* __restrict__ gPrev,
    const float* __restrict__ bePrev, float* yout, float* __restrict__ statsOut,
    float* __restrict__ ymax, float* __restrict__ ymin) {
  constexpr int NC = CO/16;
  __shared__ float4 Ws4[64*CO/4];
  __shared__ float scIn[64], shIn[64];
  __shared__ float scratch[2*CO];
  float* Ws = (float*)Ws4;

  int t = threadIdx.x;
  int tc = t & 15;
  int wv = t >> 6;
  int trs = (t >> 4) & 3;
  if (t < 64) {
    float mean = statsPrev[t] * (1.0f/MROWS);
    float var  = statsPrev[64+t] * (1.0f/MROWS) - mean*mean;
    float inv  = 1.0f / sqrtf(var + EPSV);
    float sc   = gPrev[t] * inv;
    scIn[t] = sc; shIn[t] = bePrev[t] - mean*sc;
  }
  for (int idx = t; idx < 64*CO; idx += 256) {
    int cc = idx / CO, o = idx % CO;
    Ws[cc*CO + o] = W[o*64 + cc];
  }
  float bj[NC], accS[NC], accQ[NC];
#pragma unroll
  for (int j = 0; j < NC; ++j) { bj[j] = bias[tc*NC + j]; accS[j] = 0.f; accQ[j] = 0.f; }
  __syncthreads();

  for (int tile = blockIdx.x; tile < MROWS/128; tile += gridDim.x) {
    const float4* src = (const float4*)(xin + (size_t)tile*128*64);

    float acc[8][NC];
#pragma unroll
    for (int i = 0; i < 8; ++i)
#pragma unroll
      for (int j = 0; j < NC; ++j) acc[i][j] = bj[j];

    for (int c4 = 0; c4 < 16; ++c4) {
      float4 a[8];
#pragma unroll
      for (int i = 0; i < 8; ++i) a[i] = src[(size_t)(32*wv + trs + 4*i)*16 + c4];
      float4 sc4 = ((const float4*)scIn)[c4];
      float4 sh4 = ((const float4*)shIn)[c4];
#pragma unroll
      for (int i = 0; i < 8; ++i) {
        a[i].x = fmaxf(0.f, fmaf(a[i].x, sc4.x, sh4.x));
        a[i].y = fmaxf(0.f, fmaf(a[i].y, sc4.y, sh4.y));
        a[i].z = fmaxf(0.f, fmaf(a[i].z, sc4.z, sh4.z));
        a[i].w = fmaxf(0.f, fmaf(a[i].w, sc4.w, sh4.w));
      }
      float4 w[4][NC/4];
#pragma unroll
      for (int cc = 0; cc < 4; ++cc)
#pragma unroll
        for (int q = 0; q < NC/4; ++q)
          w[cc][q] = Ws4[(4*c4 + cc)*(CO/4) + tc*(NC/4) + q];
#pragma unroll
      for (int cc = 0; cc < 4; ++cc) {
#pragma unroll
        for (int i = 0; i < 8; ++i) {
          float av = (cc==0) ? a[i].x : (cc==1) ? a[i].y : (cc==2) ? a[i].z : a[i].w;
#pragma unroll
          for (int q = 0; q < NC/4; ++q) {
            acc[i][4*q+0] = fmaf(av, w[cc][q].x, acc[i][4*q+0]);
            acc[i][4*q+1] = fmaf(av, w[cc][q].y, acc[i][4*q+1]);
            acc[i][4*q+2] = fmaf(av, w[cc][q].z, acc[i][4*q+2]);
            acc[i][4*q+3] = fmaf(av, w[cc][q].w, acc[i][4*q+3]);
          }
        }
      }
    }

    if constexpr (MODE <= 1) {
#pragma unroll
      for (int i = 0; i < 8; ++i) {
        size_t rw = (size_t)tile*128 + 32*wv + trs + 4*i;
        float4 v = make_float4(acc[i][0], acc[i][1], acc[i][2], acc[i][3]);
        ((float4*)(yout + rw*64))[tc] = v;
      }
    }
#pragma unroll
    for (int i = 0; i < 8; ++i)
#pragma unroll
      for (int j = 0; j < NC; ++j) {
        float v = acc[i][j];
        accS[j] += v;
        accQ[j] = fmaf(v, v, accQ[j]);
      }

    if constexpr (MODE == 2) {
      float vmx[NC], vmn[NC];
#pragma unroll
      for (int j = 0; j < NC; ++j) {
        float mx = acc[0][j], mn = acc[0][j];
#pragma unroll
        for (int i = 1; i < 8; ++i) { mx = fmaxf(mx, acc[i][j]); mn = fminf(mn, acc[i][j]); }
        vmx[j] = mx; vmn[j] = mn;
      }
#pragma unroll
      for (int m = 16; m <= 32; m <<= 1)
#pragma unroll
        for (int j = 0; j < NC; ++j) {
          vmx[j] = fmaxf(vmx[j], __shfl_xor(vmx[j], m, 64));
          vmn[j] = fminf(vmn[j], __shfl_xor(vmn[j], m, 64));
        }
      if ((t & 63) < 16) {
        size_t gg = (size_t)tile*4 + wv;
        ((float4*)(ymax + gg*128 + 8*tc))[0] = make_float4(vmx[0], vmx[1], vmx[2], vmx[3]);
        ((float4*)(ymax + gg*128 + 8*tc))[1] = make_float4(vmx[4], vmx[5], vmx[6], vmx[7]);
        ((float4*)(ymin + gg*128 + 8*tc))[0] = make_float4(vmn[0], vmn[1], vmn[2], vmn[3]);
        ((float4*)(ymin + gg*128 + 8*tc))[1] = make_float4(vmn[4], vmn[5], vmn[6], vmn[7]);
      }
    }
  }

  __syncthreads();
  if (t < 2*CO) scratch[t] = 0.f;
  __syncthreads();
#pragma unroll
  for (int j = 0; j < NC; ++j) {
    atomicAdd(&scratch[tc*NC + j], accS[j]);
    atomicAdd(&scratch[CO + tc*NC + j], accQ[j]);
  }
  __syncthreads();
  if (t < 2*CO) atomicAdd(&statsOut[t], scratch[t]);
}

// ---------------- epilogue: BN2+relu on max/min-pooled conv2, transposed write ----------------
__global__ __launch_bounds__(256) void final_kernel(const float4* __restrict__ ymax4,
                                                    const float4* __restrict__ ymin4,
                                                    const float* __restrict__ stats2,
                                                    const float* __restrict__ g2,
                                                    const float* __restrict__ be2,
                                                    float* __restrict__ out) {
  __shared__ float sc3[128], sh3[128];
  __shared__ float tile[64*129];
  int t = threadIdx.x;
  if (t < 128) {
    float mean = stats2[t] * (1.0f/MROWS);
    float var  = stats2[128+t] * (1.0f/MROWS) - mean*mean;
    float sc   = g2[t] / sqrtf(var + EPSV);
    sc3[t] = sc; sh3[t] = be2[t] - mean*sc;
  }
  __syncthreads();
  int b = blockIdx.x, s0 = blockIdx.y*64;
#pragma unroll
  for (int pass = 0; pass < 8; ++pass) {
    int srow = pass*8 + (t >> 5);
    int o4 = (t & 31)*4;
    size_t base = (size_t)(b*SS + s0 + srow)*32 + (t & 31);
    float4 vx = ymax4[base], vn = ymin4[base];
#pragma unroll
    for (int e = 0; e < 4; ++e) {
      int o = o4 + e;
      float sc = sc3[o];
      float v = sc > 0.f ? ((const float*)&vx)[e] : ((const float*)&vn)[e];
      tile[srow*129 + o] = fmaxf(0.f, fmaf(v, sc, sh3[o]));
    }
  }
  __syncthreads();
  int s = t & 63;
  size_t obase = (size_t)OUT_OFF1 + (size_t)b*128*SS + s0 + s;
#pragma unroll
  for (int oi = 0; oi < 32; ++oi) {
    int o = (t >> 6) + 4*oi;
    out[obase + (size_t)o*SS] = tile[s*129 + o];
  }
}

extern "C" void kernel_launch(void* const* d_in, const int* in_sizes, int n_in,
                              void* d_out, int out_size, void* d_ws, size_t ws_size,
                              hipStream_t stream) {
  const float* xyz = (const float*)d_in[0];
  const float* pts = (const float*)d_in[1];
  const float* W0  = (const float*)d_in[2];
  const float* b0  = (const float*)d_in[3];
  const float* g0  = (const float*)d_in[4];
  const float* be0 = (const float*)d_in[5];
  const float* W1  = (const float*)d_in[6];
  const float* b1  = (const float*)d_in[7];
  const float* g1  = (const float*)d_in[8];
  const float* be1 = (const float*)d_in[9];
  const float* W2  = (const float*)d_in[10];
  const float* b2  = (const float*)d_in[11];
  const float* g2  = (const float*)d_in[12];
  const float* be2 = (const float*)d_in[13];
  float* out = (float*)d_out;
  char* ws = (char*)d_ws;

  float4* xyzt   = (float4*)(ws + OFF_XYZT);
  float4* newxyz = (float4*)(ws + OFF_NEWXYZ);
  float*  stats  = (float*)(ws + OFF_STATS);
  int*    prog   = (int*)(ws + OFF_PROG);
  float*  pt     = (float*)(ws + OFF_PT);
  float*  y      = (float*)(ws + OFF_Y);
  float*  ymax   = (float*)(ws + OFF_YMAX);
  float*  ymin   = (float*)(ws + OFF_YMIN);

  hipMemsetAsync(stats, 0, 2048 + 256, stream);   // stats + progress counters
  trans_kernel<<<BB*(NN/64), 256, 0, stream>>>(xyz, pts, xyzt, pt);
  fps_ball_conv0<<<16 + BB*SS/4, 256, 0, stream>>>(
      xyz, (const float4*)xyzt, pt, newxyz, prog, out, W0, b0, y, stats);
  conv_kernel<1,64><<<2048, 256, 0, stream>>>(y, W1, b1,
      stats, g0, be0, y, stats+128, nullptr, nullptr);
  conv_kernel<2,128><<<2048, 256, 0, stream>>>(y, W2, b2,
      stats+128, g1, be1, nullptr, stats+256, ymax, ymin);
  final_kernel<<<dim3(BB, SS/64), 256, 0, stream>>>((const float4*)ymax, (const float4*)ymin,
      stats+256, g2, be2, out);
}

// Round 9
// 1148.383 us; speedup vs baseline: 1.0908x; 1.0908x over previous
//
#include <hip/hip_runtime.h>
#include <cstdint>
#include <cstddef>

#define BB 16
#define NN 4096
#define SS 1024
#define KK 32
#define MROWS (BB*SS*KK)   // 524288 rows, one per (b,s,k)
#define EPSV 1e-5f
#define OUT_OFF1 (BB*3*SS) // 49152 floats: new_xyz chunk size

// ---------------- workspace layout (bytes) ----------------
static constexpr size_t OFF_XYZT   = 0;                                    // float4[B*N]
static constexpr size_t OFF_NEWXYZ = OFF_XYZT   + (size_t)BB*NN*16;        // float4[B*S]
static constexpr size_t OFF_BALL   = OFF_NEWXYZ + (size_t)BB*SS*16;        // int[M] (unused now)
static constexpr size_t OFF_STATS  = OFF_BALL   + (size_t)MROWS*4;         // float[512]
static constexpr size_t OFF_PROG   = OFF_STATS  + 2048;                    // int[64]: [0..15] FPS progress
static constexpr size_t OFF_PT     = OFF_PROG   + 256;                     // float[B*N*64]
static constexpr size_t OFF_Y      = OFF_PT     + (size_t)BB*NN*64*4;      // float[M*64] 134MB
static constexpr size_t OFF_YMAX   = OFF_Y      + (size_t)MROWS*64*4;      // float[B*S*128]
static constexpr size_t OFF_YMIN   = OFF_YMAX   + (size_t)BB*SS*128*4;     // float[B*S*128]

// Non-contractible fp32 ops: numpy computes mul+add (never FMA). hipcc ignores
// `#pragma clang fp contract(off)` for device code (proven rounds 1-8) — the
// _rn intrinsics are the only reliable way to match np's discrete decisions.
__device__ __forceinline__ float sq3(float x, float y, float z) {
  return __fadd_rn(__fadd_rn(__fmul_rn(x,x), __fmul_rn(y,y)), __fmul_rn(z,z));
}

// u64 max with a DPP-shifted partner (r1-proven): VALU-latency lane exchange.
// row_shr:1/2/4/8 + row_bcast15 + row_bcast31; full-wave max lands in lane 63.
template<int CTRL>
__device__ __forceinline__ unsigned long long dpp_max_u64(unsigned long long k) {
  int lo = (int)(unsigned)k;
  int hi = (int)(unsigned)(k >> 32);
  unsigned olo = (unsigned)__builtin_amdgcn_update_dpp(0, lo, CTRL, 0xf, 0xf, true);
  unsigned ohi = (unsigned)__builtin_amdgcn_update_dpp(0, hi, CTRL, 0xf, 0xf, true);
  unsigned long long o = ((unsigned long long)ohi << 32) | (unsigned long long)olo;
  return o > k ? o : k;
}

// ---------------- standalone transpose prologue ----------------
// No dependencies; runs before the mega kernel. The kernel boundary (same
// stream) guarantees pt/xyzt visibility to every later block.
__global__ __launch_bounds__(256) void trans_kernel(const float* __restrict__ xyz,
                                                    const float* __restrict__ pts,
                                                    float4* __restrict__ xyzt,
                                                    float* __restrict__ pt) {
  __shared__ float tl[64*65];
  int t = threadIdx.x;
  int k = blockIdx.x;                 // 1024 blocks: b = k>>6, n0 = (k&63)*64
  int b = k >> 6, n0 = (k & 63) * 64;
  int ln = t & 63, hi = t >> 6;
#pragma unroll
  for (int i = 0; i < 16; ++i) {
    int c = 4*i + hi;
    tl[c*65 + ln] = pts[((size_t)b*64 + c)*NN + n0 + ln];
  }
  if (t < 64) {
    int n = n0 + t;
    const float* xb = xyz + (size_t)b*3*NN;
    xyzt[(size_t)b*NN + n] = make_float4(xb[n], xb[NN+n], xb[2*NN+n], 0.f);
  }
  __syncthreads();
#pragma unroll
  for (int i = 0; i < 16; ++i) {
    int nn = hi + 4*i;
    pt[((size_t)b*NN + n0 + nn)*64 + ln] = tl[ln*65 + nn];
  }
}

// ---------------- mega kernel (r3-proven best) ----------------
// blocks 0-15    : FPS (round-10 u64 form + r1 store-batching, barrier reduce)
// blocks 16-4111 : fused ball query + conv0 tile (128 rows each), dependency
//                  prog[b] only (r0/r1-proven safe class).
// LDS union: FPS 65600 B, fused 52736 B -> 65600 B static, 2 blocks/CU.
// Session ledger: FPS micro-levers all refuted (setprio r4, CU-exclusive r5,
// 8-wave r6, spin-reduce r7); conv global-direct refuted (r8). This is the
// measured optimum structure (1156-1159 us total).
__global__ __launch_bounds__(256) void fps_ball_conv0(const float* __restrict__ xyz,
                                                      const float4* __restrict__ xyzt,
                                                      const float* __restrict__ pt,
                                                      float4* __restrict__ newxyz,
                                                      int* __restrict__ prog,
                                                      float* __restrict__ out,
                                                      const float* __restrict__ W0,
                                                      const float* __restrict__ bias0,
                                                      float* __restrict__ y,
                                                      float* __restrict__ stats0) {
  __shared__ __align__(16) char smem[65600];
  int t = threadIdx.x;

  if (blockIdx.x >= 16) {
    // ---------------- fused ball query + conv0 (one 128-row tile) ----------------
    float4* Ws4  = (float4*)smem;                 // [0, 17408)   68x64 weights
    float*  Ws   = (float*)Ws4;
    float4* Xs4  = (float4*)(smem + 17408);       // [17408, 52224) 128x68 tile
    int*    bidx = (int*)(smem + 52224);          // [52224, 52736) ball indices
    int lane = t & 63, wv = t >> 6;
    int base = (blockIdx.x - 16)*4;               // 4 consecutive bs
    int bs = base + wv;
    int b = bs >> 10;

    // W0 preload overlaps the wait (no dependency). Column order matches the
    // proven MODE0 layout: [points64, xyz3, zero-pad].
    for (int idx = t; idx < 68*64; idx += 256) {
      int cc = idx >> 6, o = idx & 63;
      float v = 0.f;
      if (cc < 67) v = W0[o*67 + (cc < 64 ? cc+3 : cc-64)];
      Ws[(cc << 6) + o] = v;
    }

    // Single poller (r1 poll-storm fix), FPS progress only.
    int need = (base & (SS-1)) + 4;
    if (t == 0) {
      while (__hip_atomic_load(&prog[b], __ATOMIC_ACQUIRE, __HIP_MEMORY_SCOPE_AGENT) < need)
        __builtin_amdgcn_s_sleep(64);
    }
    __syncthreads();

    // ---- ball query (verified ballot form), indices to LDS ----
    const float* xb = xyz + (size_t)b*3*NN;
    float4 c = newxyz[bs];
    float sumS = sq3(c.x, c.y, c.z);
    int count = 0;
    for (int ch = 0; ch < NN/64; ++ch) {
      int n = ch*64 + lane;
      float nx = xb[n], ny = xb[NN+n], nz = xb[2*NN+n];
      float sumN = sq3(nx, ny, nz);
      float dt   = __fadd_rn(__fadd_rn(__fmul_rn(c.x,nx), __fmul_rn(c.y,ny)), __fmul_rn(c.z,nz));
      float sqr  = __fsub_rn(__fadd_rn(sumS, sumN), __fmul_rn(2.0f, dt));
      bool isin = !(sqr > 0.04f);
      unsigned long long mask = __ballot(isin);
      int pos = count + (int)__popcll(mask & ((1ull << lane) - 1ull));
      if (isin && pos < KK) bidx[(wv << 5) + pos] = n;
      count += (int)__popcll(mask);
      if (count >= KK) break;
    }
    if (count < KK && lane >= count && lane < KK) bidx[(wv << 5) + lane] = NN-1;
    __syncthreads();

    // ---- gather (MODE0 form, ball index from LDS) ----
    {
      int rr = t >> 1, p = t & 1;
      int n = bidx[rr];
      const float4* src = (const float4*)(pt + ((size_t)(b*NN + n))*64) + 8*p;
#pragma unroll
      for (int jj = 0; jj < 8; ++jj) Xs4[rr*17 + 8*p + jj] = src[jj];
      if (p == 0) {
        float4 pz = xyzt[b*NN + n];
        float4 q  = newxyz[base + (rr >> 5)];
        float* X = (float*)Xs4;
        X[rr*68 + 64] = pz.x - q.x;
        X[rr*68 + 65] = pz.y - q.y;
        X[rr*68 + 66] = pz.z - q.z;
        X[rr*68 + 67] = 0.f;
      }
    }
    __syncthreads();

    // ---- conv0 GEMM (exact MODE0 inner loop, CO=64, CR=68) ----
    int tc = t & 15, trs = (t >> 4) & 3;
    float accS[4], accQ[4];
#pragma unroll
    for (int j = 0; j < 4; ++j) { accS[j] = 0.f; accQ[j] = 0.f; }

    float acc[8][4];
#pragma unroll
    for (int i = 0; i < 8; ++i)
#pragma unroll
      for (int j = 0; j < 4; ++j) acc[i][j] = bias0[tc*4 + j];

    for (int c4 = 0; c4 < 17; ++c4) {
      float4 a[8];
#pragma unroll
      for (int i = 0; i < 8; ++i) a[i] = Xs4[(32*wv + trs + 4*i)*17 + c4];
      float4 w[4];
#pragma unroll
      for (int cc = 0; cc < 4; ++cc) w[cc] = Ws4[(4*c4 + cc)*16 + tc];
#pragma unroll
      for (int cc = 0; cc < 4; ++cc) {
#pragma unroll
        for (int i = 0; i < 8; ++i) {
          float av = (cc==0) ? a[i].x : (cc==1) ? a[i].y : (cc==2) ? a[i].z : a[i].w;
          acc[i][0] = fmaf(av, w[cc].x, acc[i][0]);
          acc[i][1] = fmaf(av, w[cc].y, acc[i][1]);
          acc[i][2] = fmaf(av, w[cc].z, acc[i][2]);
          acc[i][3] = fmaf(av, w[cc].w, acc[i][3]);
        }
      }
    }

#pragma unroll
    for (int i = 0; i < 8; ++i) {
      size_t rw = (size_t)base*32 + 32*wv + trs + 4*i;
      ((float4*)(y + rw*64))[tc] = make_float4(acc[i][0], acc[i][1], acc[i][2], acc[i][3]);
    }
#pragma unroll
    for (int i = 0; i < 8; ++i)
#pragma unroll
      for (int j = 0; j < 4; ++j) {
        float v = acc[i][j];
        accS[j] += v;
        accQ[j] = fmaf(v, v, accQ[j]);
      }

    __syncthreads();
    float* scratch = (float*)Xs4;
    if (t < 128) scratch[t] = 0.f;
    __syncthreads();
#pragma unroll
    for (int j = 0; j < 4; ++j) {
      atomicAdd(&scratch[tc*4 + j], accS[j]);
      atomicAdd(&scratch[64 + tc*4 + j], accQ[j]);
    }
    __syncthreads();
    if (t < 128) atomicAdd(&stats0[t], scratch[t]);
    return;
  }

  // ---------------- FPS (round-10 u64 form + r1 store-batch, float4 LDS) ----------------
  float4* sxyz = (float4*)smem;                                   // [0, 65536)
  unsigned long long (*red)[4] = (unsigned long long (*)[4])(smem + 65536);
  int b = blockIdx.x;
  int lane = t & 63, wv = t >> 6;
  const float* xb = xyz + (size_t)b*3*NN;
  float px[16], py[16], pz[16], dd[16];
#pragma unroll
  for (int j = 0; j < 16; ++j) {
    int n = t + 256*j;
    px[j] = xb[n]; py[j] = xb[NN+n]; pz[j] = xb[2*NN+n];
    sxyz[n] = make_float4(px[j], py[j], pz[j], 0.f);
    dd[j] = 1e10f;
  }
  int f = 0;
  float mcx = 0.f, mcy = 0.f, mcz = 0.f;   // captured centroid (wave-0 lanes 0-31)
  __syncthreads();
  for (int i = 0; i < SS; ++i) {
    float4 cc4 = sxyz[f];                  // one ds_read_b128 (uniform broadcast)
    float cx = cc4.x, cy = cc4.y, cz = cc4.z;
    if (t == (i & 31)) { mcx = cx; mcy = cy; mcz = cz; }
    if ((i & 31) == 31) {
      if (t < 32) {
        int ci = i - 31 + t;
        newxyz[b*SS + ci] = make_float4(mcx, mcy, mcz, 0.f);
        out[(size_t)b*3*SS + ci]        = mcx;
        out[(size_t)b*3*SS + SS + ci]   = mcy;
        out[(size_t)b*3*SS + 2*SS + ci] = mcz;
      }
      // release by lane 0: wave-wide vmcnt(0) before the release store covers
      // lanes 1-31's flush stores above.
      if (t == 0)
        __hip_atomic_store(&prog[b], i+1, __ATOMIC_RELEASE, __HIP_MEMORY_SCOPE_AGENT);
    }
    if (i == SS-1) break;
    unsigned long long key[16];
#pragma unroll
    for (int j = 0; j < 16; ++j) {
      float dx = __fsub_rn(px[j], cx);
      float dy = __fsub_rn(py[j], cy);
      float dz = __fsub_rn(pz[j], cz);
      float d  = sq3(dx, dy, dz);                // ((dx^2+dy^2)+dz^2), no FMA
      float nd = dd[j] < d ? dd[j] : d;
      dd[j] = nd;
      key[j] = (((unsigned long long)__float_as_uint(nd)) << 32)
             | (unsigned)(NN-1 - (t + 256*j));
    }
#pragma unroll
    for (int w = 8; w >= 1; w >>= 1)
#pragma unroll
      for (int q = 0; q < w; ++q)
        key[q] = key[q] > key[q+w] ? key[q] : key[q+w];
    unsigned long long bk = key[0];
    bk = dpp_max_u64<0x111>(bk);   // row_shr:1
    bk = dpp_max_u64<0x112>(bk);   // row_shr:2
    bk = dpp_max_u64<0x114>(bk);   // row_shr:4
    bk = dpp_max_u64<0x118>(bk);   // row_shr:8  -> lane 15 of each row16 has row max
    bk = dpp_max_u64<0x142>(bk);   // row_bcast15
    bk = dpp_max_u64<0x143>(bk);   // row_bcast31 -> lane 63 has full-wave max
    if (lane == 63) red[i&1][wv] = bk;
    __syncthreads();
    unsigned long long best = red[i&1][0];
#pragma unroll
    for (int w = 1; w < 4; ++w) { unsigned long long v = red[i&1][w]; if (v > best) best = v; }
    f = (NN-1) - (int)(best & 0xffffffffull);
  }
}

// ---------------- store-y conv passes (round-2 verified structure) ----------------
// LDS-staged X (r8 post-mortem: staging's coalesced bulk loads hide HBM
// latency; direct broadcast global reads expose ~900cy per c4 step — slower).
// MODE 1: read y, apply BN0+relu, conv 64->64, write y in-place, stats1
// MODE 2: read y, apply BN1+relu, conv 64->128, stats2, per-(b,s) max&min over k
template<int MODE, int CO>
__global__ __launch_bounds__(256) void conv_kernel(
    const float* xin, const float* __restrict__ W, const float* __restrict__ bias,
    const float* __restrict__ statsPrev, const float* __restrict__ gPrev,
    const float* __restrict__ bePrev, float* yout, float* __restrict__ statsOut,
    float* __restrict__ ymax, float* __restrict__ ymin) {
  constexpr int NC = CO/16;
  constexpr int CR = 64;                      // W rows in LDS
  constexpr int C4N = CR/4;
  __shared__ float4 Ws4[CR*CO/4];
  __shared__ float4 Xs4[128*17];              // 128 rows x 68 cols
  __shared__ float scIn[64], shIn[64];
  float* Ws = (float*)Ws4;

  int t = threadIdx.x;
  int tc = t & 15;
  int wv = t >> 6;
  int trs = (t >> 4) & 3;
  if (t < 64) {
    float mean = statsPrev[t] * (1.0f/MROWS);
    float var  = statsPrev[64+t] * (1.0f/MROWS) - mean*mean;
    float inv  = 1.0f / sqrtf(var + EPSV);
    float sc   = gPrev[t] * inv;
    scIn[t] = sc; shIn[t] = bePrev[t] - mean*sc;
  }
  for (int idx = t; idx < CR*CO; idx += 256) {
    int cc = idx / CO, o = idx % CO;
    Ws[cc*CO + o] = W[o*64 + cc];
  }
  float bj[NC], accS[NC], accQ[NC];
#pragma unroll
  for (int j = 0; j < NC; ++j) { bj[j] = bias[tc*NC + j]; accS[j] = 0.f; accQ[j] = 0.f; }
  __syncthreads();

  for (int tile = blockIdx.x; tile < MROWS/128; tile += gridDim.x) {
    {
      const float4* src = (const float4*)(xin + (size_t)tile*128*64);
#pragma unroll
      for (int k = 0; k < 8; ++k) {
        int idx = t + 256*k;
        int row = idx >> 4, c4 = idx & 15;
        float4 v = src[idx];
        int c = 4*c4;
        v.x = fmaxf(0.f, fmaf(v.x, scIn[c+0], shIn[c+0]));
        v.y = fmaxf(0.f, fmaf(v.y, scIn[c+1], shIn[c+1]));
        v.z = fmaxf(0.f, fmaf(v.z, scIn[c+2], shIn[c+2]));
        v.w = fmaxf(0.f, fmaf(v.w, scIn[c+3], shIn[c+3]));
        Xs4[row*17 + c4] = v;
      }
    }
    __syncthreads();

    float acc[8][NC];
#pragma unroll
    for (int i = 0; i < 8; ++i)
#pragma unroll
      for (int j = 0; j < NC; ++j) acc[i][j] = bj[j];

    for (int c4 = 0; c4 < C4N; ++c4) {
      float4 a[8];
#pragma unroll
      for (int i = 0; i < 8; ++i) a[i] = Xs4[(32*wv + trs + 4*i)*17 + c4];
      float4 w[4][NC/4];
#pragma unroll
      for (int cc = 0; cc < 4; ++cc)
#pragma unroll
        for (int q = 0; q < NC/4; ++q)
          w[cc][q] = Ws4[(4*c4 + cc)*(CO/4) + tc*(NC/4) + q];
#pragma unroll
      for (int cc = 0; cc < 4; ++cc) {
#pragma unroll
        for (int i = 0; i < 8; ++i) {
          float av = (cc==0) ? a[i].x : (cc==1) ? a[i].y : (cc==2) ? a[i].z : a[i].w;
#pragma unroll
          for (int q = 0; q < NC/4; ++q) {
            acc[i][4*q+0] = fmaf(av, w[cc][q].x, acc[i][4*q+0]);
            acc[i][4*q+1] = fmaf(av, w[cc][q].y, acc[i][4*q+1]);
            acc[i][4*q+2] = fmaf(av, w[cc][q].z, acc[i][4*q+2]);
            acc[i][4*q+3] = fmaf(av, w[cc][q].w, acc[i][4*q+3]);
          }
        }
      }
    }

    if constexpr (MODE <= 1) {
#pragma unroll
      for (int i = 0; i < 8; ++i) {
        size_t rw = (size_t)tile*128 + 32*wv + trs + 4*i;
        float4 v = make_float4(acc[i][0], acc[i][1], acc[i][2], acc[i][3]);
        ((float4*)(yout + rw*64))[tc] = v;
      }
    }
#pragma unroll
    for (int i = 0; i < 8; ++i)
#pragma unroll
      for (int j = 0; j < NC; ++j) {
        float v = acc[i][j];
        accS[j] += v;
        accQ[j] = fmaf(v, v, accQ[j]);
      }

    if constexpr (MODE == 2) {
      float vmx[NC], vmn[NC];
#pragma unroll
      for (int j = 0; j < NC; ++j) {
        float mx = acc[0][j], mn = acc[0][j];
#pragma unroll
        for (int i = 1; i < 8; ++i) { mx = fmaxf(mx, acc[i][j]); mn = fminf(mn, acc[i][j]); }
        vmx[j] = mx; vmn[j] = mn;
      }
#pragma unroll
      for (int m = 16; m <= 32; m <<= 1)
#pragma unroll
        for (int j = 0; j < NC; ++j) {
          vmx[j] = fmaxf(vmx[j], __shfl_xor(vmx[j], m, 64));
          vmn[j] = fminf(vmn[j], __shfl_xor(vmn[j], m, 64));
        }
      if ((t & 63) < 16) {
        size_t gg = (size_t)tile*4 + wv;
        ((float4*)(ymax + gg*128 + 8*tc))[0] = make_float4(vmx[0], vmx[1], vmx[2], vmx[3]);
        ((float4*)(ymax + gg*128 + 8*tc))[1] = make_float4(vmx[4], vmx[5], vmx[6], vmx[7]);
        ((float4*)(ymin + gg*128 + 8*tc))[0] = make_float4(vmn[0], vmn[1], vmn[2], vmn[3]);
        ((float4*)(ymin + gg*128 + 8*tc))[1] = make_float4(vmn[4], vmn[5], vmn[6], vmn[7]);
      }
    }
    __syncthreads();
  }

  float* scratch = (float*)Xs4;
  if (t < 2*CO) scratch[t] = 0.f;
  __syncthreads();
#pragma unroll
  for (int j = 0; j < NC; ++j) {
    atomicAdd(&scratch[tc*NC + j], accS[j]);
    atomicAdd(&scratch[CO + tc*NC + j], accQ[j]);
  }
  __syncthreads();
  if (t < 2*CO) atomicAdd(&statsOut[t], scratch[t]);
}

// ---------------- epilogue: BN2+relu on max/min-pooled conv2, transposed write ----------------
__global__ __launch_bounds__(256) void final_kernel(const float4* __restrict__ ymax4,
                                                    const float4* __restrict__ ymin4,
                                                    const float* __restrict__ stats2,
                                                    const float* __restrict__ g2,
                                                    const float* __restrict__ be2,
                                                    float* __restrict__ out) {
  __shared__ float sc3[128], sh3[128];
  __shared__ float tile[64*129];
  int t = threadIdx.x;
  if (t < 128) {
    float mean = stats2[t] * (1.0f/MROWS);
    float var  = stats2[128+t] * (1.0f/MROWS) - mean*mean;
    float sc   = g2[t] / sqrtf(var + EPSV);
    sc3[t] = sc; sh3[t] = be2[t] - mean*sc;
  }
  __syncthreads();
  int b = blockIdx.x, s0 = blockIdx.y*64;
#pragma unroll
  for (int pass = 0; pass < 8; ++pass) {
    int srow = pass*8 + (t >> 5);
    int o4 = (t & 31)*4;
    size_t base = (size_t)(b*SS + s0 + srow)*32 + (t & 31);
    float4 vx = ymax4[base], vn = ymin4[base];
#pragma unroll
    for (int e = 0; e < 4; ++e) {
      int o = o4 + e;
      float sc = sc3[o];
      float v = sc > 0.f ? ((const float*)&vx)[e] : ((const float*)&vn)[e];
      tile[srow*129 + o] = fmaxf(0.f, fmaf(v, sc, sh3[o]));
    }
  }
  __syncthreads();
  int s = t & 63;
  size_t obase = (size_t)OUT_OFF1 + (size_t)b*128*SS + s0 + s;
#pragma unroll
  for (int oi = 0; oi < 32; ++oi) {
    int o = (t >> 6) + 4*oi;
    out[obase + (size_t)o*SS] = tile[s*129 + o];
  }
}

extern "C" void kernel_launch(void* const* d_in, const int* in_sizes, int n_in,
                              void* d_out, int out_size, void* d_ws, size_t ws_size,
                              hipStream_t stream) {
  const float* xyz = (const float*)d_in[0];
  const float* pts = (const float*)d_in[1];
  const float* W0  = (const float*)d_in[2];
  const float* b0  = (const float*)d_in[3];
  const float* g0  = (const float*)d_in[4];
  const float* be0 = (const float*)d_in[5];
  const float* W1  = (const float*)d_in[6];
  const float* b1  = (const float*)d_in[7];
  const float* g1  = (const float*)d_in[8];
  const float* be1 = (const float*)d_in[9];
  const float* W2  = (const float*)d_in[10];
  const float* b2  = (const float*)d_in[11];
  const float* g2  = (const float*)d_in[12];
  const float* be2 = (const float*)d_in[13];
  float* out = (float*)d_out;
  char* ws = (char*)d_ws;

  float4* xyzt   = (float4*)(ws + OFF_XYZT);
  float4* newxyz = (float4*)(ws + OFF_NEWXYZ);
  float*  stats  = (float*)(ws + OFF_STATS);
  int*    prog   = (int*)(ws + OFF_PROG);
  float*  pt     = (float*)(ws + OFF_PT);
  float*  y      = (float*)(ws + OFF_Y);
  float*  ymax   = (float*)(ws + OFF_YMAX);
  float*  ymin   = (float*)(ws + OFF_YMIN);

  hipMemsetAsync(stats, 0, 2048 + 256, stream);   // stats + progress counters
  trans_kernel<<<BB*(NN/64), 256, 0, stream>>>(xyz, pts, xyzt, pt);
  fps_ball_conv0<<<16 + BB*SS/4, 256, 0, stream>>>(
      xyz, (const float4*)xyzt, pt, newxyz, prog, out, W0, b0, y, stats);
  conv_kernel<1,64><<<1024, 256, 0, stream>>>(y, W1, b1,
      stats, g0, be0, y, stats+128, nullptr, nullptr);
  conv_kernel<2,128><<<1024, 256, 0, stream>>>(y, W2, b2,
      stats+128, g1, be1, nullptr, stats+256, ymax, ymin);
  final_kernel<<<dim3(BB, SS/64), 256, 0, stream>>>((const float4*)ymax, (const float4*)ymin,
      stats+256, g2, be2, out);
}